// Round 1
// baseline (1694.489 us; speedup 1.0000x reference)
//
#include <hip/hip_runtime.h>
#include <math.h>

#define NA 50000
#define NE 800000
#define FDIM 128
#define KDIM 64
#define NRI 3
#define NRA 2

#define ROWS 32
#define LDSP 132   // padded LDS row stride (floats): 16B-aligned, breaks pow2 bank pattern

__device__ __forceinline__ float ssp_f(float x) {
    // jax.nn.softplus(x) - log(2) ; softplus = logaddexp(x,0) = max(x,0)+log1p(exp(-|x|))
    return fmaxf(x, 0.0f) + log1pf(__expf(-fabsf(x))) - 0.69314718055994530942f;
}

// ---------------------------------------------------------------------------
// Node pre: xa = ssp(feat); xi = ssp(xa@Wi.T+bi) -> out_xi ; xj = ssp(xa@Wj.T+bj) -> out_xj
// ---------------------------------------------------------------------------
__global__ __launch_bounds__(256) void k_node_pre(
    const float* __restrict__ feat,
    const float* __restrict__ Wi, const float* __restrict__ bi,
    const float* __restrict__ Wj, const float* __restrict__ bj,
    float* __restrict__ out_xi, float* __restrict__ out_xj)
{
    __shared__ float xs[ROWS][LDSP];
    __shared__ float ws[64][LDSP];
    const int t = threadIdx.x;
    const int row0 = blockIdx.x * ROWS;

    for (int idx = t; idx < ROWS * FDIM; idx += 256) {
        int r = idx >> 7, c = idx & 127;
        int gr = row0 + r;
        xs[r][c] = (gr < NA) ? ssp_f(feat[(size_t)gr * FDIM + c]) : 0.0f;
    }

    const int tc = t & 31, tr = t >> 5;
    for (int sel = 0; sel < 2; ++sel) {
        const float* W = sel ? Wj : Wi;
        const float* b = sel ? bj : bi;
        float* outp    = sel ? out_xj : out_xi;
        for (int ch = 0; ch < 2; ++ch) {
            __syncthreads();
            for (int idx = t; idx < 64 * FDIM; idx += 256) {
                int r = idx >> 7, c = idx & 127;
                ws[r][c] = W[(size_t)(ch * 64 + r) * FDIM + c];
            }
            __syncthreads();
            float acc[4][2] = {};
            for (int k = 0; k < FDIM; k += 4) {
                float4 xv[4], wv[2];
                #pragma unroll
                for (int i = 0; i < 4; ++i) xv[i] = *(const float4*)&xs[tr * 4 + i][k];
                #pragma unroll
                for (int j = 0; j < 2; ++j) wv[j] = *(const float4*)&ws[tc + 32 * j][k];
                #pragma unroll
                for (int i = 0; i < 4; ++i)
                    #pragma unroll
                    for (int j = 0; j < 2; ++j)
                        acc[i][j] += xv[i].x * wv[j].x + xv[i].y * wv[j].y
                                   + xv[i].z * wv[j].z + xv[i].w * wv[j].w;
            }
            #pragma unroll
            for (int i = 0; i < 4; ++i)
                #pragma unroll
                for (int j = 0; j < 2; ++j) {
                    int gr = row0 + tr * 4 + i;
                    int gc = ch * 64 + tc + 32 * j;
                    if (gr < NA)
                        outp[(size_t)gr * FDIM + gc] = ssp_f(acc[i][j] + b[gc]);
                }
        }
    }
}

// ---------------------------------------------------------------------------
// Edge aggregation: msg[i] += sum_{e: idx_i[e]==i} (desc[e] @ Wdesc.T) * xj_all[idx_j[e]]
// idx_i sorted -> one block per atom, binary-searched segment, non-atomic RMW.
// ---------------------------------------------------------------------------
__global__ __launch_bounds__(128) void k_edge(
    const float* __restrict__ desc,
    const int* __restrict__ idx_i,
    const int* __restrict__ idx_j,
    const float* __restrict__ Wdesc,
    const float* __restrict__ xj_all,
    float* __restrict__ msg)
{
    const int i = blockIdx.x;
    const int t = threadIdx.x;   // t == output feature f

    // lower_bound(idx_i, i) and lower_bound(idx_i, i+1), computed redundantly per lane
    int lo = 0, hi = NE;
    while (lo < hi) { int mid = (lo + hi) >> 1; if (idx_i[mid] < i) lo = mid + 1; else hi = mid; }
    int start = lo;
    hi = NE;
    while (lo < hi) { int mid = (lo + hi) >> 1; if (idx_i[mid] < i + 1) lo = mid + 1; else hi = mid; }
    int end = lo;
    // force wave-uniform (SGPR) so desc loads scalarize
    start = __builtin_amdgcn_readfirstlane(start);
    end   = __builtin_amdgcn_readfirstlane(end);
    if (start >= end) return;

    float wreg[KDIM];
    #pragma unroll
    for (int q = 0; q < KDIM / 4; ++q) {
        float4 wv = *(const float4*)(Wdesc + (size_t)t * KDIM + 4 * q);
        wreg[4*q+0] = wv.x; wreg[4*q+1] = wv.y; wreg[4*q+2] = wv.z; wreg[4*q+3] = wv.w;
    }

    float acc = 0.0f;
    for (int e = start; e < end; ++e) {
        int jj = idx_j[e];                       // wave-uniform
        const float* de = desc + (size_t)e * KDIM; // wave-uniform address -> s_load
        float dot = 0.0f;
        #pragma unroll
        for (int q = 0; q < KDIM / 4; ++q) {
            float4 dv = *(const float4*)(de + 4 * q);
            dot += dv.x * wreg[4*q] + dv.y * wreg[4*q+1]
                 + dv.z * wreg[4*q+2] + dv.w * wreg[4*q+3];
        }
        acc += dot * xj_all[(size_t)jj * FDIM + t];
    }
    msg[(size_t)i * FDIM + t] += acc;
}

// ---------------------------------------------------------------------------
// Fused residual layer: m = m + ssp(ssp(m)@W1.T+b1)@W2.T + b2   (in-place safe, row-local)
// ---------------------------------------------------------------------------
__global__ __launch_bounds__(256) void k_residual(
    const float* __restrict__ m_in,
    const float* __restrict__ W1, const float* __restrict__ b1,
    const float* __restrict__ W2, const float* __restrict__ b2,
    float* __restrict__ m_out)
{
    __shared__ float ys[ROWS][LDSP];
    __shared__ float hs[ROWS][LDSP];
    __shared__ float ws[64][LDSP];
    const int t = threadIdx.x;
    const int row0 = blockIdx.x * ROWS;

    for (int idx = t; idx < ROWS * FDIM; idx += 256) {
        int r = idx >> 7, c = idx & 127;
        int gr = row0 + r;
        ys[r][c] = (gr < NA) ? ssp_f(m_in[(size_t)gr * FDIM + c]) : 0.0f;
    }

    const int tc = t & 31, tr = t >> 5;

    // GEMM1: hs = ssp(ys @ W1.T + b1)
    for (int ch = 0; ch < 2; ++ch) {
        __syncthreads();
        for (int idx = t; idx < 64 * FDIM; idx += 256) {
            int r = idx >> 7, c = idx & 127;
            ws[r][c] = W1[(size_t)(ch * 64 + r) * FDIM + c];
        }
        __syncthreads();
        float acc[4][2] = {};
        for (int k = 0; k < FDIM; k += 4) {
            float4 xv[4], wv[2];
            #pragma unroll
            for (int i = 0; i < 4; ++i) xv[i] = *(const float4*)&ys[tr * 4 + i][k];
            #pragma unroll
            for (int j = 0; j < 2; ++j) wv[j] = *(const float4*)&ws[tc + 32 * j][k];
            #pragma unroll
            for (int i = 0; i < 4; ++i)
                #pragma unroll
                for (int j = 0; j < 2; ++j)
                    acc[i][j] += xv[i].x * wv[j].x + xv[i].y * wv[j].y
                               + xv[i].z * wv[j].z + xv[i].w * wv[j].w;
        }
        #pragma unroll
        for (int i = 0; i < 4; ++i)
            #pragma unroll
            for (int j = 0; j < 2; ++j) {
                int gc = ch * 64 + tc + 32 * j;
                hs[tr * 4 + i][gc] = ssp_f(acc[i][j] + b1[gc]);
            }
    }

    // GEMM2: out = m + hs @ W2.T + b2
    for (int ch = 0; ch < 2; ++ch) {
        __syncthreads();
        for (int idx = t; idx < 64 * FDIM; idx += 256) {
            int r = idx >> 7, c = idx & 127;
            ws[r][c] = W2[(size_t)(ch * 64 + r) * FDIM + c];
        }
        __syncthreads();
        float acc[4][2] = {};
        for (int k = 0; k < FDIM; k += 4) {
            float4 xv[4], wv[2];
            #pragma unroll
            for (int i = 0; i < 4; ++i) xv[i] = *(const float4*)&hs[tr * 4 + i][k];
            #pragma unroll
            for (int j = 0; j < 2; ++j) wv[j] = *(const float4*)&ws[tc + 32 * j][k];
            #pragma unroll
            for (int i = 0; i < 4; ++i)
                #pragma unroll
                for (int j = 0; j < 2; ++j)
                    acc[i][j] += xv[i].x * wv[j].x + xv[i].y * wv[j].y
                               + xv[i].z * wv[j].z + xv[i].w * wv[j].w;
        }
        #pragma unroll
        for (int i = 0; i < 4; ++i)
            #pragma unroll
            for (int j = 0; j < 2; ++j) {
                int gr = row0 + tr * 4 + i;
                int gc = ch * 64 + tc + 32 * j;
                if (gr < NA)
                    m_out[(size_t)gr * FDIM + gc] =
                        m_in[(size_t)gr * FDIM + gc] + acc[i][j] + b2[gc];
            }
    }
}

// ---------------------------------------------------------------------------
// Output mix: x = u*feat + ssp(msg) @ Wd.T + bd
// ---------------------------------------------------------------------------
__global__ __launch_bounds__(256) void k_outmix(
    const float* __restrict__ msg,
    const float* __restrict__ feat,
    const float* __restrict__ Wd, const float* __restrict__ bd,
    const float* __restrict__ u,
    float* __restrict__ xout)
{
    __shared__ float ys[ROWS][LDSP];
    __shared__ float ws[64][LDSP];
    const int t = threadIdx.x;
    const int row0 = blockIdx.x * ROWS;

    for (int idx = t; idx < ROWS * FDIM; idx += 256) {
        int r = idx >> 7, c = idx & 127;
        int gr = row0 + r;
        ys[r][c] = (gr < NA) ? ssp_f(msg[(size_t)gr * FDIM + c]) : 0.0f;
    }

    const int tc = t & 31, tr = t >> 5;
    for (int ch = 0; ch < 2; ++ch) {
        __syncthreads();
        for (int idx = t; idx < 64 * FDIM; idx += 256) {
            int r = idx >> 7, c = idx & 127;
            ws[r][c] = Wd[(size_t)(ch * 64 + r) * FDIM + c];
        }
        __syncthreads();
        float acc[4][2] = {};
        for (int k = 0; k < FDIM; k += 4) {
            float4 xv[4], wv[2];
            #pragma unroll
            for (int i = 0; i < 4; ++i) xv[i] = *(const float4*)&ys[tr * 4 + i][k];
            #pragma unroll
            for (int j = 0; j < 2; ++j) wv[j] = *(const float4*)&ws[tc + 32 * j][k];
            #pragma unroll
            for (int i = 0; i < 4; ++i)
                #pragma unroll
                for (int j = 0; j < 2; ++j)
                    acc[i][j] += xv[i].x * wv[j].x + xv[i].y * wv[j].y
                               + xv[i].z * wv[j].z + xv[i].w * wv[j].w;
        }
        #pragma unroll
        for (int i = 0; i < 4; ++i)
            #pragma unroll
            for (int j = 0; j < 2; ++j) {
                int gr = row0 + tr * 4 + i;
                int gc = ch * 64 + tc + 32 * j;
                if (gr < NA)
                    xout[(size_t)gr * FDIM + gc] =
                        u[gc] * feat[(size_t)gr * FDIM + gc] + acc[i][j] + bd[gc];
            }
    }
}

// ---------------------------------------------------------------------------
extern "C" void kernel_launch(void* const* d_in, const int* in_sizes, int n_in,
                              void* d_out, int out_size, void* d_ws, size_t ws_size,
                              hipStream_t stream)
{
    const float* feat  = (const float*)d_in[0];
    const float* desc  = (const float*)d_in[1];
    const int*   idx_i = (const int*)d_in[2];
    const int*   idx_j = (const int*)d_in[3];
    const float* Wdesc = (const float*)d_in[4];
    const float* Wi    = (const float*)d_in[5];
    const float* bi    = (const float*)d_in[6];
    const float* Wj    = (const float*)d_in[7];
    const float* bj    = (const float*)d_in[8];
    const float* Wri1  = (const float*)d_in[9];
    const float* bri1  = (const float*)d_in[10];
    const float* Wri2  = (const float*)d_in[11];
    const float* bri2  = (const float*)d_in[12];
    const float* Wd    = (const float*)d_in[13];
    const float* bd    = (const float*)d_in[14];
    const float* u     = (const float*)d_in[15];
    const float* Wra1  = (const float*)d_in[16];
    const float* bra1  = (const float*)d_in[17];
    const float* Wra2  = (const float*)d_in[18];
    const float* bra2  = (const float*)d_in[19];

    float* msg  = (float*)d_ws;                       // N*F floats (message accumulator)
    float* xja  = msg + (size_t)NA * FDIM;            // N*F floats (xj_all)
    float* xout = (float*)d_out;

    const int nblk = (NA + ROWS - 1) / ROWS;

    k_node_pre<<<nblk, 256, 0, stream>>>(feat, Wi, bi, Wj, bj, msg, xja);
    k_edge<<<NA, 128, 0, stream>>>(desc, idx_i, idx_j, Wdesc, xja, msg);
    for (int k = 0; k < NRI; ++k)
        k_residual<<<nblk, 256, 0, stream>>>(msg,
            Wri1 + (size_t)k * FDIM * FDIM, bri1 + (size_t)k * FDIM,
            Wri2 + (size_t)k * FDIM * FDIM, bri2 + (size_t)k * FDIM, msg);
    k_outmix<<<nblk, 256, 0, stream>>>(msg, feat, Wd, bd, u, xout);
    for (int k = 0; k < NRA; ++k)
        k_residual<<<nblk, 256, 0, stream>>>(xout,
            Wra1 + (size_t)k * FDIM * FDIM, bra1 + (size_t)k * FDIM,
            Wra2 + (size_t)k * FDIM * FDIM, bra2 + (size_t)k * FDIM, xout);
}

// Round 2
// 1336.960 us; speedup vs baseline: 1.2674x; 1.2674x over previous
//
#include <hip/hip_runtime.h>
#include <math.h>

#define NA 50000
#define NE 800000
#define FDIM 128
#define KDIM 64
#define NRI 3
#define NRA 2

#define ROWS 32
#define LDSP 132   // padded LDS row stride (floats)

typedef unsigned short ushort_t;
typedef __attribute__((ext_vector_type(8))) short short8v;
typedef __attribute__((ext_vector_type(4))) float f32x4;

__device__ __forceinline__ float ssp_f(float x) {
    return fmaxf(x, 0.0f) + log1pf(__expf(-fabsf(x))) - 0.69314718055994530942f;
}
__device__ __forceinline__ ushort_t f2bf(float x) {
    unsigned u = __float_as_uint(x);
    u += 0x7FFFu + ((u >> 16) & 1u);          // round-to-nearest-even
    return (ushort_t)(u >> 16);
}
__device__ __forceinline__ float bf2f(ushort_t h) {
    return __uint_as_float(((unsigned)h) << 16);
}

// ---------------------------------------------------------------------------
// Node pre: xa = ssp(feat); out_xi = ssp(xa@Wi.T+bi); out_xj = ssp(xa@Wj.T+bj)
// ---------------------------------------------------------------------------
__global__ __launch_bounds__(256) void k_node_pre(
    const float* __restrict__ feat,
    const float* __restrict__ Wi, const float* __restrict__ bi,
    const float* __restrict__ Wj, const float* __restrict__ bj,
    float* __restrict__ out_xi, float* __restrict__ out_xj)
{
    __shared__ float xs[ROWS][LDSP];
    __shared__ float ws[64][LDSP];
    const int t = threadIdx.x;
    const int row0 = blockIdx.x * ROWS;

    for (int idx = t; idx < ROWS * FDIM; idx += 256) {
        int r = idx >> 7, c = idx & 127;
        int gr = row0 + r;
        xs[r][c] = (gr < NA) ? ssp_f(feat[(size_t)gr * FDIM + c]) : 0.0f;
    }

    const int tc = t & 31, tr = t >> 5;
    for (int sel = 0; sel < 2; ++sel) {
        const float* W = sel ? Wj : Wi;
        const float* b = sel ? bj : bi;
        float* outp    = sel ? out_xj : out_xi;
        for (int ch = 0; ch < 2; ++ch) {
            __syncthreads();
            for (int idx = t; idx < 64 * FDIM; idx += 256) {
                int r = idx >> 7, c = idx & 127;
                ws[r][c] = W[(size_t)(ch * 64 + r) * FDIM + c];
            }
            __syncthreads();
            float acc[4][2] = {};
            for (int k = 0; k < FDIM; k += 4) {
                float4 xv[4], wv[2];
                #pragma unroll
                for (int i = 0; i < 4; ++i) xv[i] = *(const float4*)&xs[tr * 4 + i][k];
                #pragma unroll
                for (int j = 0; j < 2; ++j) wv[j] = *(const float4*)&ws[tc + 32 * j][k];
                #pragma unroll
                for (int i = 0; i < 4; ++i)
                    #pragma unroll
                    for (int j = 0; j < 2; ++j)
                        acc[i][j] += xv[i].x * wv[j].x + xv[i].y * wv[j].y
                                   + xv[i].z * wv[j].z + xv[i].w * wv[j].w;
            }
            #pragma unroll
            for (int i = 0; i < 4; ++i)
                #pragma unroll
                for (int j = 0; j < 2; ++j) {
                    int gr = row0 + tr * 4 + i;
                    int gc = ch * 64 + tc + 32 * j;
                    if (gr < NA)
                        outp[(size_t)gr * FDIM + gc] = ssp_f(acc[i][j] + b[gc]);
                }
        }
    }
}

// ---------------------------------------------------------------------------
// Per-atom segment starts: row_start[i] = lower_bound(idx_i, i); row_start[NA]=NE
// ---------------------------------------------------------------------------
__global__ __launch_bounds__(256) void k_row_starts(
    const int* __restrict__ idx_i, int* __restrict__ row_start)
{
    int i = blockIdx.x * 256 + threadIdx.x;
    if (i > NA) return;
    if (i == NA) { row_start[NA] = NE; return; }
    int lo = 0, hi = NE;
    while (lo < hi) { int mid = (lo + hi) >> 1; if (idx_i[mid] < i) lo = mid + 1; else hi = mid; }
    row_start[i] = lo;
}

// ---------------------------------------------------------------------------
// Edge GEMM (MFMA bf16): g[e][f] = sum_k desc[e][k] * Wdesc[f][k], g stored bf16
// Tile: 64 edges x 128 features, 256 threads (4 waves, 16 edge-rows each)
// ---------------------------------------------------------------------------
__global__ __launch_bounds__(256) void k_gemm_g(
    const float* __restrict__ desc,      // chunk base, [nE][64]
    const float* __restrict__ Wdesc,     // [128][64]
    ushort_t* __restrict__ g,            // chunk base, [nE][128] bf16
    int nE)
{
    __shared__ ushort_t sW[128][72];     // +8 pad: 144B stride -> ~2-way (free)
    __shared__ ushort_t sD[64][72];
    const int t = threadIdx.x;
    const int e0 = blockIdx.x * 64;

    for (int idx = t; idx < 128 * 64; idx += 256) {
        int r = idx >> 6, c = idx & 63;
        sW[r][c] = f2bf(Wdesc[idx]);
    }
    for (int idx = t; idx < 64 * 64; idx += 256) {
        int r = idx >> 6, c = idx & 63;
        int ge = e0 + r;
        sD[r][c] = (ge < nE) ? f2bf(desc[(size_t)ge * 64 + c]) : (ushort_t)0;
    }
    __syncthreads();

    const int lane = t & 63;
    const int w    = t >> 6;       // wave id: edge rows [w*16, w*16+16)
    const int lrow = lane & 15;
    const int kgrp = lane >> 4;    // 0..3

    short8v a[2];
    #pragma unroll
    for (int ks = 0; ks < 2; ++ks)
        a[ks] = *(const short8v*)&sD[w * 16 + lrow][ks * 32 + kgrp * 8];

    f32x4 acc[8];
    #pragma unroll
    for (int nf = 0; nf < 8; ++nf) acc[nf] = (f32x4){0.f, 0.f, 0.f, 0.f};

    #pragma unroll
    for (int nf = 0; nf < 8; ++nf) {
        #pragma unroll
        for (int ks = 0; ks < 2; ++ks) {
            short8v b = *(const short8v*)&sW[nf * 16 + lrow][ks * 32 + kgrp * 8];
            acc[nf] = __builtin_amdgcn_mfma_f32_16x16x32_bf16(a[ks], b, acc[nf], 0, 0, 0);
        }
    }

    #pragma unroll
    for (int nf = 0; nf < 8; ++nf)
        #pragma unroll
        for (int r = 0; r < 4; ++r) {
            int eloc = e0 + w * 16 + kgrp * 4 + r;   // M row = (lane>>4)*4 + reg
            if (eloc < nE)
                g[(size_t)eloc * FDIM + nf * 16 + lrow] = f2bf(acc[nf][r]);
        }
}

// ---------------------------------------------------------------------------
// Scatter: msg[i][t] += sum_{e in seg(i) ∩ [ce0,ce1)} g[e-ce0][t] * xja[idx_j[e]][t]
// One block per atom; only block i writes row i -> deterministic, no atomics.
// ---------------------------------------------------------------------------
__global__ __launch_bounds__(128) void k_scatter(
    const ushort_t* __restrict__ g,
    const int* __restrict__ row_start,
    const int* __restrict__ idx_j,
    const float* __restrict__ xja,
    float* __restrict__ msg,
    int ce0, int ce1)
{
    const int i = blockIdx.x;
    const int t = threadIdx.x;
    int s = row_start[i], e = row_start[i + 1];
    if (s < ce0) s = ce0;
    if (e > ce1) e = ce1;
    if (s >= e) return;
    float acc = 0.0f;
    for (int k = s; k < e; ++k) {
        int jj = idx_j[k];
        acc += bf2f(g[(size_t)(k - ce0) * FDIM + t]) * xja[(size_t)jj * FDIM + t];
    }
    msg[(size_t)i * FDIM + t] += acc;
}

// ---------------------------------------------------------------------------
// Fallback fused edge kernel (used only if workspace too small for g chunks)
// ---------------------------------------------------------------------------
__global__ __launch_bounds__(128) void k_edge(
    const float* __restrict__ desc,
    const int* __restrict__ idx_i,
    const int* __restrict__ idx_j,
    const float* __restrict__ Wdesc,
    const float* __restrict__ xj_all,
    float* __restrict__ msg)
{
    const int i = blockIdx.x;
    const int t = threadIdx.x;
    int lo = 0, hi = NE;
    while (lo < hi) { int mid = (lo + hi) >> 1; if (idx_i[mid] < i) lo = mid + 1; else hi = mid; }
    int start = lo;
    hi = NE;
    while (lo < hi) { int mid = (lo + hi) >> 1; if (idx_i[mid] < i + 1) lo = mid + 1; else hi = mid; }
    int end = lo;
    start = __builtin_amdgcn_readfirstlane(start);
    end   = __builtin_amdgcn_readfirstlane(end);
    if (start >= end) return;

    float wreg[KDIM];
    #pragma unroll
    for (int q = 0; q < KDIM / 4; ++q) {
        float4 wv = *(const float4*)(Wdesc + (size_t)t * KDIM + 4 * q);
        wreg[4*q+0] = wv.x; wreg[4*q+1] = wv.y; wreg[4*q+2] = wv.z; wreg[4*q+3] = wv.w;
    }
    float acc = 0.0f;
    for (int e = start; e < end; ++e) {
        int jj = idx_j[e];
        const float* de = desc + (size_t)e * KDIM;
        float dot = 0.0f;
        #pragma unroll
        for (int q = 0; q < KDIM / 4; ++q) {
            float4 dv = *(const float4*)(de + 4 * q);
            dot += dv.x * wreg[4*q] + dv.y * wreg[4*q+1]
                 + dv.z * wreg[4*q+2] + dv.w * wreg[4*q+3];
        }
        acc += dot * xj_all[(size_t)jj * FDIM + t];
    }
    msg[(size_t)i * FDIM + t] += acc;
}

// ---------------------------------------------------------------------------
// Fused residual layer: m_out = m_in + ssp(ssp(m_in)@W1.T+b1)@W2.T + b2
// ---------------------------------------------------------------------------
__global__ __launch_bounds__(256) void k_residual(
    const float* __restrict__ m_in,
    const float* __restrict__ W1, const float* __restrict__ b1,
    const float* __restrict__ W2, const float* __restrict__ b2,
    float* __restrict__ m_out)
{
    __shared__ float ys[ROWS][LDSP];
    __shared__ float hs[ROWS][LDSP];
    __shared__ float ws[64][LDSP];
    const int t = threadIdx.x;
    const int row0 = blockIdx.x * ROWS;

    for (int idx = t; idx < ROWS * FDIM; idx += 256) {
        int r = idx >> 7, c = idx & 127;
        int gr = row0 + r;
        ys[r][c] = (gr < NA) ? ssp_f(m_in[(size_t)gr * FDIM + c]) : 0.0f;
    }

    const int tc = t & 31, tr = t >> 5;

    for (int ch = 0; ch < 2; ++ch) {
        __syncthreads();
        for (int idx = t; idx < 64 * FDIM; idx += 256) {
            int r = idx >> 7, c = idx & 127;
            ws[r][c] = W1[(size_t)(ch * 64 + r) * FDIM + c];
        }
        __syncthreads();
        float acc[4][2] = {};
        for (int k = 0; k < FDIM; k += 4) {
            float4 xv[4], wv[2];
            #pragma unroll
            for (int i = 0; i < 4; ++i) xv[i] = *(const float4*)&ys[tr * 4 + i][k];
            #pragma unroll
            for (int j = 0; j < 2; ++j) wv[j] = *(const float4*)&ws[tc + 32 * j][k];
            #pragma unroll
            for (int i = 0; i < 4; ++i)
                #pragma unroll
                for (int j = 0; j < 2; ++j)
                    acc[i][j] += xv[i].x * wv[j].x + xv[i].y * wv[j].y
                               + xv[i].z * wv[j].z + xv[i].w * wv[j].w;
        }
        #pragma unroll
        for (int i = 0; i < 4; ++i)
            #pragma unroll
            for (int j = 0; j < 2; ++j) {
                int gc = ch * 64 + tc + 32 * j;
                hs[tr * 4 + i][gc] = ssp_f(acc[i][j] + b1[gc]);
            }
    }

    for (int ch = 0; ch < 2; ++ch) {
        __syncthreads();
        for (int idx = t; idx < 64 * FDIM; idx += 256) {
            int r = idx >> 7, c = idx & 127;
            ws[r][c] = W2[(size_t)(ch * 64 + r) * FDIM + c];
        }
        __syncthreads();
        float acc[4][2] = {};
        for (int k = 0; k < FDIM; k += 4) {
            float4 xv[4], wv[2];
            #pragma unroll
            for (int i = 0; i < 4; ++i) xv[i] = *(const float4*)&hs[tr * 4 + i][k];
            #pragma unroll
            for (int j = 0; j < 2; ++j) wv[j] = *(const float4*)&ws[tc + 32 * j][k];
            #pragma unroll
            for (int i = 0; i < 4; ++i)
                #pragma unroll
                for (int j = 0; j < 2; ++j)
                    acc[i][j] += xv[i].x * wv[j].x + xv[i].y * wv[j].y
                               + xv[i].z * wv[j].z + xv[i].w * wv[j].w;
        }
        #pragma unroll
        for (int i = 0; i < 4; ++i)
            #pragma unroll
            for (int j = 0; j < 2; ++j) {
                int gr = row0 + tr * 4 + i;
                int gc = ch * 64 + tc + 32 * j;
                if (gr < NA)
                    m_out[(size_t)gr * FDIM + gc] =
                        m_in[(size_t)gr * FDIM + gc] + acc[i][j] + b2[gc];
            }
    }
}

// ---------------------------------------------------------------------------
// Output mix: x = u*feat + ssp(msg) @ Wd.T + bd
// ---------------------------------------------------------------------------
__global__ __launch_bounds__(256) void k_outmix(
    const float* __restrict__ msg,
    const float* __restrict__ feat,
    const float* __restrict__ Wd, const float* __restrict__ bd,
    const float* __restrict__ u,
    float* __restrict__ xout)
{
    __shared__ float ys[ROWS][LDSP];
    __shared__ float ws[64][LDSP];
    const int t = threadIdx.x;
    const int row0 = blockIdx.x * ROWS;

    for (int idx = t; idx < ROWS * FDIM; idx += 256) {
        int r = idx >> 7, c = idx & 127;
        int gr = row0 + r;
        ys[r][c] = (gr < NA) ? ssp_f(msg[(size_t)gr * FDIM + c]) : 0.0f;
    }

    const int tc = t & 31, tr = t >> 5;
    for (int ch = 0; ch < 2; ++ch) {
        __syncthreads();
        for (int idx = t; idx < 64 * FDIM; idx += 256) {
            int r = idx >> 7, c = idx & 127;
            ws[r][c] = Wd[(size_t)(ch * 64 + r) * FDIM + c];
        }
        __syncthreads();
        float acc[4][2] = {};
        for (int k = 0; k < FDIM; k += 4) {
            float4 xv[4], wv[2];
            #pragma unroll
            for (int i = 0; i < 4; ++i) xv[i] = *(const float4*)&ys[tr * 4 + i][k];
            #pragma unroll
            for (int j = 0; j < 2; ++j) wv[j] = *(const float4*)&ws[tc + 32 * j][k];
            #pragma unroll
            for (int i = 0; i < 4; ++i)
                #pragma unroll
                for (int j = 0; j < 2; ++j)
                    acc[i][j] += xv[i].x * wv[j].x + xv[i].y * wv[j].y
                               + xv[i].z * wv[j].z + xv[i].w * wv[j].w;
        }
        #pragma unroll
        for (int i = 0; i < 4; ++i)
            #pragma unroll
            for (int j = 0; j < 2; ++j) {
                int gr = row0 + tr * 4 + i;
                int gc = ch * 64 + tc + 32 * j;
                if (gr < NA)
                    xout[(size_t)gr * FDIM + gc] =
                        u[gc] * feat[(size_t)gr * FDIM + gc] + acc[i][j] + bd[gc];
            }
    }
}

// ---------------------------------------------------------------------------
extern "C" void kernel_launch(void* const* d_in, const int* in_sizes, int n_in,
                              void* d_out, int out_size, void* d_ws, size_t ws_size,
                              hipStream_t stream)
{
    const float* feat  = (const float*)d_in[0];
    const float* desc  = (const float*)d_in[1];
    const int*   idx_i = (const int*)d_in[2];
    const int*   idx_j = (const int*)d_in[3];
    const float* Wdesc = (const float*)d_in[4];
    const float* Wi    = (const float*)d_in[5];
    const float* bi    = (const float*)d_in[6];
    const float* Wj    = (const float*)d_in[7];
    const float* bj    = (const float*)d_in[8];
    const float* Wri1  = (const float*)d_in[9];
    const float* bri1  = (const float*)d_in[10];
    const float* Wri2  = (const float*)d_in[11];
    const float* bri2  = (const float*)d_in[12];
    const float* Wd    = (const float*)d_in[13];
    const float* bd    = (const float*)d_in[14];
    const float* u     = (const float*)d_in[15];
    const float* Wra1  = (const float*)d_in[16];
    const float* bra1  = (const float*)d_in[17];
    const float* Wra2  = (const float*)d_in[18];
    const float* bra2  = (const float*)d_in[19];

    char* wsp = (char*)d_ws;
    float* msg = (float*)wsp;                              // NA*F
    float* xja = msg + (size_t)NA * FDIM;                  // NA*F
    size_t base = (size_t)2 * NA * FDIM * sizeof(float);
    int* row_start = (int*)(wsp + base);                   // NA+1 ints
    size_t rs_bytes = (((size_t)(NA + 1) * sizeof(int)) + 255) & ~(size_t)255;
    ushort_t* gbuf = (ushort_t*)(wsp + base + rs_bytes);
    size_t avail = (ws_size > base + rs_bytes) ? ws_size - base - rs_bytes : 0;
    size_t max_chunk = (avail / ((size_t)FDIM * sizeof(ushort_t))) & ~(size_t)63;

    float* xout = (float*)d_out;
    const int nblk = (NA + ROWS - 1) / ROWS;

    k_node_pre<<<nblk, 256, 0, stream>>>(feat, Wi, bi, Wj, bj, msg, xja);

    if (max_chunk >= 4096) {
        k_row_starts<<<(NA + 256) / 256, 256, 0, stream>>>(idx_i, row_start);
        for (size_t ce0 = 0; ce0 < NE; ce0 += max_chunk) {
            size_t ce1 = ce0 + max_chunk; if (ce1 > NE) ce1 = NE;
            int n = (int)(ce1 - ce0);
            k_gemm_g<<<(n + 63) / 64, 256, 0, stream>>>(desc + ce0 * KDIM, Wdesc, gbuf, n);
            k_scatter<<<NA, 128, 0, stream>>>(gbuf, row_start, idx_j, xja, msg,
                                              (int)ce0, (int)ce1);
        }
    } else {
        k_edge<<<NA, 128, 0, stream>>>(desc, idx_i, idx_j, Wdesc, xja, msg);
    }

    for (int k = 0; k < NRI; ++k)
        k_residual<<<nblk, 256, 0, stream>>>(msg,
            Wri1 + (size_t)k * FDIM * FDIM, bri1 + (size_t)k * FDIM,
            Wri2 + (size_t)k * FDIM * FDIM, bri2 + (size_t)k * FDIM, msg);
    k_outmix<<<nblk, 256, 0, stream>>>(msg, feat, Wd, bd, u, xout);
    for (int k = 0; k < NRA; ++k)
        k_residual<<<nblk, 256, 0, stream>>>(xout,
            Wra1 + (size_t)k * FDIM * FDIM, bra1 + (size_t)k * FDIM,
            Wra2 + (size_t)k * FDIM * FDIM, bra2 + (size_t)k * FDIM, xout);
}

// Round 3
// 619.033 us; speedup vs baseline: 2.7373x; 2.1598x over previous
//
#include <hip/hip_runtime.h>
#include <math.h>

#define NA 50000
#define NE 800000
#define FDIM 128
#define KDIM 64
#define NRI 3
#define NRA 2

typedef unsigned short ushort_t;
typedef __attribute__((ext_vector_type(8))) short short8v;
typedef __attribute__((ext_vector_type(4))) float f32x4;

__device__ __forceinline__ float ssp_f(float x) {
    return fmaxf(x, 0.0f) + log1pf(__expf(-fabsf(x))) - 0.69314718055994530942f;
}
__device__ __forceinline__ ushort_t f2bf(float x) {
    unsigned u = __float_as_uint(x);
    u += 0x7FFFu + ((u >> 16) & 1u);          // RNE
    return (ushort_t)(u >> 16);
}
__device__ __forceinline__ float bf2f(ushort_t h) {
    return __uint_as_float(((unsigned)h) << 16);
}

// ---------------------------------------------------------------------------
// Weight pre-convert: all fp32 weight matrices -> bf16 in ws, once.
// wbf layout (ushort offsets): Wdesc@0 (8192), Wi@8192, Wj@24576,
// chain@40960: [Wri1_0,Wri2_0,Wri1_1,Wri2_1,Wri1_2,Wri2_2,Wd,Wra1_0,Wra2_0,Wra1_1,Wra2_1]
// ---------------------------------------------------------------------------
__global__ __launch_bounds__(256) void k_wconv(
    const float* __restrict__ Wdesc, const float* __restrict__ Wi,
    const float* __restrict__ Wj,    const float* __restrict__ Wri1,
    const float* __restrict__ Wri2,  const float* __restrict__ Wd,
    const float* __restrict__ Wra1,  const float* __restrict__ Wra2,
    ushort_t* __restrict__ wbf)
{
    const int seg = blockIdx.y;
    const int idx = blockIdx.x * 2048 + threadIdx.x * 8;
    const float* s; ushort_t* d; int cnt;
    const int CH = 40960;
    switch (seg) {
    case 0: cnt = 8192;  if (idx >= cnt) return; s = Wdesc + idx; d = wbf + idx; break;
    case 1: cnt = 16384; if (idx >= cnt) return; s = Wi + idx;    d = wbf + 8192 + idx; break;
    case 2: cnt = 16384; if (idx >= cnt) return; s = Wj + idx;    d = wbf + 24576 + idx; break;
    case 3: { cnt = 3*16384; if (idx >= cnt) return; int k = idx/16384, o = idx - k*16384;
              s = Wri1 + idx; d = wbf + CH + (2*k)*16384 + o; break; }
    case 4: { cnt = 3*16384; if (idx >= cnt) return; int k = idx/16384, o = idx - k*16384;
              s = Wri2 + idx; d = wbf + CH + (2*k+1)*16384 + o; break; }
    case 5: cnt = 16384; if (idx >= cnt) return; s = Wd + idx; d = wbf + CH + 6*16384 + idx; break;
    case 6: { cnt = 2*16384; if (idx >= cnt) return; int k = idx/16384, o = idx - k*16384;
              s = Wra1 + idx; d = wbf + CH + (7+2*k)*16384 + o; break; }
    default:{ cnt = 2*16384; if (idx >= cnt) return; int k = idx/16384, o = idx - k*16384;
              s = Wra2 + idx; d = wbf + CH + (8+2*k)*16384 + o; break; }
    }
    #pragma unroll
    for (int j = 0; j < 8; ++j) d[j] = f2bf(s[j]);
}

// ---------------------------------------------------------------------------
// Per-atom segment starts
// ---------------------------------------------------------------------------
__global__ __launch_bounds__(256) void k_row_starts(
    const int* __restrict__ idx_i, int* __restrict__ row_start)
{
    int i = blockIdx.x * 256 + threadIdx.x;
    if (i > NA) return;
    if (i == NA) { row_start[NA] = NE; return; }
    int lo = 0, hi = NE;
    while (lo < hi) { int mid = (lo + hi) >> 1; if (idx_i[mid] < i) lo = mid + 1; else hi = mid; }
    row_start[i] = lo;
}

// ---------------------------------------------------------------------------
// Shared MFMA helpers: 64-row M-tile, 256 threads, wave w owns rows [16w,16w+16)
// ---------------------------------------------------------------------------
__device__ __forceinline__ void stage_w(const ushort_t* __restrict__ src,
                                        ushort_t (*wlds)[136], int t)
{
    const int r = t >> 1, c0 = (t & 1) * 64;
    const short8v* s = (const short8v*)(src + (size_t)r * FDIM + c0);
    #pragma unroll
    for (int q = 0; q < 8; ++q)
        *(short8v*)&wlds[r][c0 + q * 8] = s[q];
}

__device__ __forceinline__ void gemm_tile(
    const ushort_t (*actA)[136], const ushort_t (*wlds)[136],
    int w, int lrow, int kgrp, const float* __restrict__ bias, f32x4 acc[8])
{
    short8v a[4];
    #pragma unroll
    for (int ks = 0; ks < 4; ++ks)
        a[ks] = *(const short8v*)&actA[16 * w + lrow][ks * 32 + kgrp * 8];
    #pragma unroll
    for (int nf = 0; nf < 8; ++nf) {
        float b = bias[nf * 16 + lrow];
        acc[nf] = (f32x4){b, b, b, b};
    }
    #pragma unroll
    for (int nf = 0; nf < 8; ++nf)
        #pragma unroll
        for (int ks = 0; ks < 4; ++ks) {
            short8v bv = *(const short8v*)&wlds[nf * 16 + lrow][ks * 32 + kgrp * 8];
            acc[nf] = __builtin_amdgcn_mfma_f32_16x16x32_bf16(a[ks], bv, acc[nf], 0, 0, 0);
        }
}

// ---------------------------------------------------------------------------
// Node pre (MFMA): xi = ssp(ssp(feat)@Wi.T+bi) -> msg (f32)
//                  xja = ssp(ssp(feat)@Wj.T+bj) -> bf16
// ---------------------------------------------------------------------------
__global__ __launch_bounds__(256) void k_node_pre(
    const float* __restrict__ feat, const ushort_t* __restrict__ wbf,
    const float* __restrict__ bi, const float* __restrict__ bj,
    float* __restrict__ xi_out, ushort_t* __restrict__ xja_out)
{
    __shared__ ushort_t actA[64][136];
    __shared__ ushort_t wlds[128][136];
    const int t = threadIdx.x, lane = t & 63, w = t >> 6;
    const int lrow = lane & 15, kgrp = lane >> 4;
    const int row0 = blockIdx.x * 64;

    #pragma unroll
    for (int nf = 0; nf < 8; ++nf)
        #pragma unroll
        for (int r = 0; r < 4; ++r) {
            int gr = row0 + 16 * w + kgrp * 4 + r;
            float x = (gr < NA) ? feat[(size_t)gr * FDIM + 16 * nf + lrow] : 0.0f;
            actA[16 * w + kgrp * 4 + r][16 * nf + lrow] = f2bf(ssp_f(x));
        }
    __syncthreads();
    stage_w(wbf + 8192, wlds, t);
    __syncthreads();
    f32x4 acc[8];
    gemm_tile(actA, wlds, w, lrow, kgrp, bi, acc);
    #pragma unroll
    for (int nf = 0; nf < 8; ++nf)
        #pragma unroll
        for (int r = 0; r < 4; ++r) {
            int gr = row0 + 16 * w + kgrp * 4 + r;
            if (gr < NA)
                xi_out[(size_t)gr * FDIM + 16 * nf + lrow] = ssp_f(acc[nf][r]);
        }
    __syncthreads();
    stage_w(wbf + 24576, wlds, t);
    __syncthreads();
    gemm_tile(actA, wlds, w, lrow, kgrp, bj, acc);
    #pragma unroll
    for (int nf = 0; nf < 8; ++nf)
        #pragma unroll
        for (int r = 0; r < 4; ++r) {
            int gr = row0 + 16 * w + kgrp * 4 + r;
            if (gr < NA)
                xja_out[(size_t)gr * FDIM + 16 * nf + lrow] = f2bf(ssp_f(acc[nf][r]));
        }
}

// ---------------------------------------------------------------------------
// Edge GEMM, LDS-free: g[e][f] = desc[e]@Wdesc[f] (bf16 out). 128 edges/block.
// ---------------------------------------------------------------------------
__device__ __forceinline__ short8v pack8(const float* p) {
    short8v r;
    #pragma unroll
    for (int j = 0; j < 8; ++j) r[j] = (short)f2bf(p[j]);
    return r;
}

__global__ __launch_bounds__(256) void k_gemm_g(
    const float* __restrict__ desc, const ushort_t* __restrict__ wdbf,
    ushort_t* __restrict__ g, int nE)
{
    const int t = threadIdx.x, lane = t & 63, w = t >> 6;
    const int lrow = lane & 15, kgrp = lane >> 4;
    const int e0 = blockIdx.x * 128 + w * 32;

    short8v a[2][2];
    #pragma unroll
    for (int mt = 0; mt < 2; ++mt)
        #pragma unroll
        for (int ks = 0; ks < 2; ++ks) {
            int er = e0 + mt * 16 + lrow;
            if (er < nE) {
                const float* p = desc + (size_t)er * KDIM + ks * 32 + kgrp * 8;
                float tmp[8];
                *(float4*)(tmp)     = *(const float4*)p;
                *(float4*)(tmp + 4) = *(const float4*)(p + 4);
                a[mt][ks] = pack8(tmp);
            } else {
                a[mt][ks] = (short8v){0,0,0,0,0,0,0,0};
            }
        }

    f32x4 acc[2][8];
    #pragma unroll
    for (int mt = 0; mt < 2; ++mt)
        #pragma unroll
        for (int nf = 0; nf < 8; ++nf) acc[mt][nf] = (f32x4){0.f,0.f,0.f,0.f};

    #pragma unroll
    for (int nf = 0; nf < 8; ++nf) {
        const size_t wo = (size_t)(16 * nf + lrow) * KDIM + kgrp * 8;
        short8v b0 = *(const short8v*)(wdbf + wo);
        short8v b1 = *(const short8v*)(wdbf + wo + 32);
        #pragma unroll
        for (int mt = 0; mt < 2; ++mt) {
            acc[mt][nf] = __builtin_amdgcn_mfma_f32_16x16x32_bf16(a[mt][0], b0, acc[mt][nf], 0,0,0);
            acc[mt][nf] = __builtin_amdgcn_mfma_f32_16x16x32_bf16(a[mt][1], b1, acc[mt][nf], 0,0,0);
        }
    }

    #pragma unroll
    for (int mt = 0; mt < 2; ++mt)
        #pragma unroll
        for (int nf = 0; nf < 8; ++nf)
            #pragma unroll
            for (int r = 0; r < 4; ++r) {
                int er = e0 + mt * 16 + kgrp * 4 + r;
                if (er < nE)
                    g[(size_t)er * FDIM + 16 * nf + lrow] = f2bf(acc[mt][nf][r]);
            }
}

// ---------------------------------------------------------------------------
// Scatter: msg[i] += sum_seg g[e]*xja[idx_j[e]]  (block per atom, deterministic)
// ---------------------------------------------------------------------------
__global__ __launch_bounds__(128) void k_scatter(
    const ushort_t* __restrict__ g,
    const int* __restrict__ row_start,
    const int* __restrict__ idx_j,
    const ushort_t* __restrict__ xja,
    float* __restrict__ msg,
    int ce0, int ce1)
{
    const int i = blockIdx.x;
    const int t = threadIdx.x;
    int s = row_start[i], e = row_start[i + 1];
    if (s < ce0) s = ce0;
    if (e > ce1) e = ce1;
    if (s >= e) return;
    float acc = 0.0f;
    for (int k = s; k < e; ++k) {
        int jj = idx_j[k];
        acc += bf2f(g[(size_t)(k - ce0) * FDIM + t]) * bf2f(xja[(size_t)jj * FDIM + t]);
    }
    msg[(size_t)i * FDIM + t] += acc;
}

// ---------------------------------------------------------------------------
// Fallback fused edge kernel (tiny-ws only)
// ---------------------------------------------------------------------------
__global__ __launch_bounds__(128) void k_edge(
    const float* __restrict__ desc,
    const int* __restrict__ idx_i,
    const int* __restrict__ idx_j,
    const float* __restrict__ Wdesc,
    const ushort_t* __restrict__ xja,
    float* __restrict__ msg)
{
    const int i = blockIdx.x;
    const int t = threadIdx.x;
    int lo = 0, hi = NE;
    while (lo < hi) { int mid = (lo + hi) >> 1; if (idx_i[mid] < i) lo = mid + 1; else hi = mid; }
    int start = lo;
    hi = NE;
    while (lo < hi) { int mid = (lo + hi) >> 1; if (idx_i[mid] < i + 1) lo = mid + 1; else hi = mid; }
    int end = lo;
    start = __builtin_amdgcn_readfirstlane(start);
    end   = __builtin_amdgcn_readfirstlane(end);
    if (start >= end) return;
    float wreg[KDIM];
    #pragma unroll
    for (int q = 0; q < KDIM / 4; ++q) {
        float4 wv = *(const float4*)(Wdesc + (size_t)t * KDIM + 4 * q);
        wreg[4*q+0] = wv.x; wreg[4*q+1] = wv.y; wreg[4*q+2] = wv.z; wreg[4*q+3] = wv.w;
    }
    float acc = 0.0f;
    for (int e = start; e < end; ++e) {
        int jj = idx_j[e];
        const float* de = desc + (size_t)e * KDIM;
        float dot = 0.0f;
        #pragma unroll
        for (int q = 0; q < KDIM / 4; ++q) {
            float4 dv = *(const float4*)(de + 4 * q);
            dot += dv.x * wreg[4*q] + dv.y * wreg[4*q+1]
                 + dv.z * wreg[4*q+2] + dv.w * wreg[4*q+3];
        }
        acc += dot * bf2f(xja[(size_t)jj * FDIM + t]);
    }
    msg[(size_t)i * FDIM + t] += acc;
}

// ---------------------------------------------------------------------------
// Fused node chain: 3 residuals + outmix + 2 residuals, m carried in registers.
// ---------------------------------------------------------------------------
__device__ __forceinline__ void write_act(
    ushort_t (*actA)[136], int w, int lrow, int kgrp, const float v[8][4])
{
    #pragma unroll
    for (int nf = 0; nf < 8; ++nf)
        #pragma unroll
        for (int r = 0; r < 4; ++r)
            actA[16 * w + kgrp * 4 + r][16 * nf + lrow] = f2bf(ssp_f(v[nf][r]));
}

__global__ __launch_bounds__(256) void k_chain(
    const float* __restrict__ msgp, const float* __restrict__ feat,
    const float* __restrict__ u, const ushort_t* __restrict__ wch,
    const float* __restrict__ bri1, const float* __restrict__ bri2,
    const float* __restrict__ bd,
    const float* __restrict__ bra1, const float* __restrict__ bra2,
    float* __restrict__ xout)
{
    __shared__ ushort_t actA[64][136];
    __shared__ ushort_t wlds[128][136];
    const int t = threadIdx.x, lane = t & 63, w = t >> 6;
    const int lrow = lane & 15, kgrp = lane >> 4;
    const int row0 = blockIdx.x * 64;

    float m[8][4];
    #pragma unroll
    for (int nf = 0; nf < 8; ++nf)
        #pragma unroll
        for (int r = 0; r < 4; ++r) {
            int gr = row0 + 16 * w + kgrp * 4 + r;
            m[nf][r] = (gr < NA) ? msgp[(size_t)gr * FDIM + 16 * nf + lrow] : 0.0f;
        }

    f32x4 acc[8];
    float h[8][4];

    // --- 3 interaction residuals ---
    for (int k = 0; k < NRI; ++k) {
        write_act(actA, w, lrow, kgrp, m);
        __syncthreads();
        stage_w(wch + (size_t)(2 * k) * 16384, wlds, t);
        __syncthreads();
        gemm_tile(actA, wlds, w, lrow, kgrp, bri1 + k * FDIM, acc);
        #pragma unroll
        for (int nf = 0; nf < 8; ++nf)
            #pragma unroll
            for (int r = 0; r < 4; ++r) h[nf][r] = acc[nf][r];
        write_act(actA, w, lrow, kgrp, h);
        __syncthreads();
        stage_w(wch + (size_t)(2 * k + 1) * 16384, wlds, t);
        __syncthreads();
        gemm_tile(actA, wlds, w, lrow, kgrp, bri2 + k * FDIM, acc);
        #pragma unroll
        for (int nf = 0; nf < 8; ++nf)
            #pragma unroll
            for (int r = 0; r < 4; ++r) m[nf][r] += acc[nf][r];
    }

    // --- outmix: m = u*feat + ssp(m)@Wd.T + bd ---
    write_act(actA, w, lrow, kgrp, m);
    __syncthreads();
    stage_w(wch + (size_t)6 * 16384, wlds, t);
    __syncthreads();
    gemm_tile(actA, wlds, w, lrow, kgrp, bd, acc);
    #pragma unroll
    for (int nf = 0; nf < 8; ++nf)
        #pragma unroll
        for (int r = 0; r < 4; ++r) {
            int gr = row0 + 16 * w + kgrp * 4 + r;
            float fv = (gr < NA) ? feat[(size_t)gr * FDIM + 16 * nf + lrow] : 0.0f;
            m[nf][r] = u[16 * nf + lrow] * fv + acc[nf][r];
        }

    // --- 2 atomic residuals ---
    for (int k = 0; k < NRA; ++k) {
        write_act(actA, w, lrow, kgrp, m);
        __syncthreads();
        stage_w(wch + (size_t)(7 + 2 * k) * 16384, wlds, t);
        __syncthreads();
        gemm_tile(actA, wlds, w, lrow, kgrp, bra1 + k * FDIM, acc);
        #pragma unroll
        for (int nf = 0; nf < 8; ++nf)
            #pragma unroll
            for (int r = 0; r < 4; ++r) h[nf][r] = acc[nf][r];
        write_act(actA, w, lrow, kgrp, h);
        __syncthreads();
        stage_w(wch + (size_t)(8 + 2 * k) * 16384, wlds, t);
        __syncthreads();
        gemm_tile(actA, wlds, w, lrow, kgrp, bra2 + k * FDIM, acc);
        #pragma unroll
        for (int nf = 0; nf < 8; ++nf)
            #pragma unroll
            for (int r = 0; r < 4; ++r) m[nf][r] += acc[nf][r];
    }

    #pragma unroll
    for (int nf = 0; nf < 8; ++nf)
        #pragma unroll
        for (int r = 0; r < 4; ++r) {
            int gr = row0 + 16 * w + kgrp * 4 + r;
            if (gr < NA)
                xout[(size_t)gr * FDIM + 16 * nf + lrow] = m[nf][r];
        }
}

// ---------------------------------------------------------------------------
extern "C" void kernel_launch(void* const* d_in, const int* in_sizes, int n_in,
                              void* d_out, int out_size, void* d_ws, size_t ws_size,
                              hipStream_t stream)
{
    const float* feat  = (const float*)d_in[0];
    const float* desc  = (const float*)d_in[1];
    const int*   idx_i = (const int*)d_in[2];
    const int*   idx_j = (const int*)d_in[3];
    const float* Wdesc = (const float*)d_in[4];
    const float* Wi    = (const float*)d_in[5];
    const float* bi    = (const float*)d_in[6];
    const float* Wj    = (const float*)d_in[7];
    const float* bj    = (const float*)d_in[8];
    const float* Wri1  = (const float*)d_in[9];
    const float* bri1  = (const float*)d_in[10];
    const float* Wri2  = (const float*)d_in[11];
    const float* bri2  = (const float*)d_in[12];
    const float* Wd    = (const float*)d_in[13];
    const float* bd    = (const float*)d_in[14];
    const float* u     = (const float*)d_in[15];
    const float* Wra1  = (const float*)d_in[16];
    const float* bra1  = (const float*)d_in[17];
    const float* Wra2  = (const float*)d_in[18];
    const float* bra2  = (const float*)d_in[19];

    char* wsp = (char*)d_ws;
    float* msg = (float*)wsp;
    size_t off = (size_t)NA * FDIM * sizeof(float);
    ushort_t* xja = (ushort_t*)(wsp + off);
    off += (size_t)NA * FDIM * sizeof(ushort_t);
    int* row_start = (int*)(wsp + off);
    off += (((size_t)(NA + 1) * sizeof(int)) + 255) & ~(size_t)255;
    ushort_t* wbf = (ushort_t*)(wsp + off);
    off += (((size_t)221184 * sizeof(ushort_t)) + 255) & ~(size_t)255;
    ushort_t* gbuf = (ushort_t*)(wsp + off);
    size_t avail = (ws_size > off) ? ws_size - off : 0;
    size_t max_chunk = (avail / ((size_t)FDIM * sizeof(ushort_t))) & ~(size_t)127;

    float* xout = (float*)d_out;
    const int nblk64 = (NA + 63) / 64;

    k_wconv<<<dim3(24, 8), 256, 0, stream>>>(Wdesc, Wi, Wj, Wri1, Wri2, Wd, Wra1, Wra2, wbf);
    k_row_starts<<<(NA + 256) / 256, 256, 0, stream>>>(idx_i, row_start);
    k_node_pre<<<nblk64, 256, 0, stream>>>(feat, wbf, bi, bj, msg, xja);

    if (max_chunk >= 128) {
        for (size_t ce0 = 0; ce0 < NE; ce0 += max_chunk) {
            size_t ce1 = ce0 + max_chunk; if (ce1 > NE) ce1 = NE;
            int n = (int)(ce1 - ce0);
            k_gemm_g<<<(n + 127) / 128, 256, 0, stream>>>(desc + ce0 * KDIM, wbf, gbuf, n);
            k_scatter<<<NA, 128, 0, stream>>>(gbuf, row_start, idx_j, xja, msg,
                                              (int)ce0, (int)ce1);
        }
    } else {
        k_edge<<<NA, 128, 0, stream>>>(desc, idx_i, idx_j, Wdesc, xja, msg);
    }

    k_chain<<<nblk64, 256, 0, stream>>>(msg, feat, u, wbf + 40960,
                                        bri1, bri2, bd, bra1, bra2, xout);
}

// Round 4
// 363.397 us; speedup vs baseline: 4.6629x; 1.7035x over previous
//
#include <hip/hip_runtime.h>
#include <math.h>

#define NA 50000
#define NE 800000
#define FDIM 128
#define KDIM 64
#define NRI 3
#define NRA 2

typedef unsigned short ushort_t;
typedef unsigned int uint_t;
typedef __attribute__((ext_vector_type(8))) short short8v;
typedef __attribute__((ext_vector_type(4))) float f32x4;

// ssp(x) = softplus(x) - ln2, via hardware v_exp_f32/v_log_f32 (~8 VALU ops).
// log1pf (libm, ~100 instr) was 60-80% of k_chain's VALU time in round 3.
__device__ __forceinline__ float ssp_f(float x) {
    float e = __expf(-fabsf(x));
    return fmaxf(x, 0.0f) + __logf(1.0f + e) - 0.69314718055994530942f;
}
__device__ __forceinline__ ushort_t f2bf(float x) {
    unsigned u = __float_as_uint(x);
    u += 0x7FFFu + ((u >> 16) & 1u);          // RNE
    return (ushort_t)(u >> 16);
}
__device__ __forceinline__ float bf2f(ushort_t h) {
    return __uint_as_float(((unsigned)h) << 16);
}

// ---------------------------------------------------------------------------
// Weight pre-convert: all fp32 weight matrices -> bf16 in ws, once.
// wbf layout (ushort offsets): Wdesc@0 (8192), Wi@8192, Wj@24576,
// chain@40960: [Wri1_0,Wri2_0,Wri1_1,Wri2_1,Wri1_2,Wri2_2,Wd,Wra1_0,Wra2_0,Wra1_1,Wra2_1]
// ---------------------------------------------------------------------------
__global__ __launch_bounds__(256) void k_wconv(
    const float* __restrict__ Wdesc, const float* __restrict__ Wi,
    const float* __restrict__ Wj,    const float* __restrict__ Wri1,
    const float* __restrict__ Wri2,  const float* __restrict__ Wd,
    const float* __restrict__ Wra1,  const float* __restrict__ Wra2,
    ushort_t* __restrict__ wbf)
{
    const int seg = blockIdx.y;
    const int idx = blockIdx.x * 2048 + threadIdx.x * 8;
    const float* s; ushort_t* d; int cnt;
    const int CH = 40960;
    switch (seg) {
    case 0: cnt = 8192;  if (idx >= cnt) return; s = Wdesc + idx; d = wbf + idx; break;
    case 1: cnt = 16384; if (idx >= cnt) return; s = Wi + idx;    d = wbf + 8192 + idx; break;
    case 2: cnt = 16384; if (idx >= cnt) return; s = Wj + idx;    d = wbf + 24576 + idx; break;
    case 3: { cnt = 3*16384; if (idx >= cnt) return; int k = idx/16384, o = idx - k*16384;
              s = Wri1 + idx; d = wbf + CH + (2*k)*16384 + o; break; }
    case 4: { cnt = 3*16384; if (idx >= cnt) return; int k = idx/16384, o = idx - k*16384;
              s = Wri2 + idx; d = wbf + CH + (2*k+1)*16384 + o; break; }
    case 5: cnt = 16384; if (idx >= cnt) return; s = Wd + idx; d = wbf + CH + 6*16384 + idx; break;
    case 6: { cnt = 2*16384; if (idx >= cnt) return; int k = idx/16384, o = idx - k*16384;
              s = Wra1 + idx; d = wbf + CH + (7+2*k)*16384 + o; break; }
    default:{ cnt = 2*16384; if (idx >= cnt) return; int k = idx/16384, o = idx - k*16384;
              s = Wra2 + idx; d = wbf + CH + (8+2*k)*16384 + o; break; }
    }
    #pragma unroll
    for (int j = 0; j < 8; ++j) d[j] = f2bf(s[j]);
}

// ---------------------------------------------------------------------------
// Per-atom segment starts
// ---------------------------------------------------------------------------
__global__ __launch_bounds__(256) void k_row_starts(
    const int* __restrict__ idx_i, int* __restrict__ row_start)
{
    int i = blockIdx.x * 256 + threadIdx.x;
    if (i > NA) return;
    if (i == NA) { row_start[NA] = NE; return; }
    int lo = 0, hi = NE;
    while (lo < hi) { int mid = (lo + hi) >> 1; if (idx_i[mid] < i) lo = mid + 1; else hi = mid; }
    row_start[i] = lo;
}

// ---------------------------------------------------------------------------
// Shared MFMA helpers: 64-row M-tile, 256 threads, wave w owns rows [16w,16w+16)
// ---------------------------------------------------------------------------
__device__ __forceinline__ void stage_w(const ushort_t* __restrict__ src,
                                        ushort_t (*wlds)[136], int t)
{
    const int r = t >> 1, c0 = (t & 1) * 64;
    const short8v* s = (const short8v*)(src + (size_t)r * FDIM + c0);
    #pragma unroll
    for (int q = 0; q < 8; ++q)
        *(short8v*)&wlds[r][c0 + q * 8] = s[q];
}

__device__ __forceinline__ void gemm_tile(
    const ushort_t (*actA)[136], const ushort_t (*wlds)[136],
    int w, int lrow, int kgrp, const float* __restrict__ bias, f32x4 acc[8])
{
    short8v a[4];
    #pragma unroll
    for (int ks = 0; ks < 4; ++ks)
        a[ks] = *(const short8v*)&actA[16 * w + lrow][ks * 32 + kgrp * 8];
    #pragma unroll
    for (int nf = 0; nf < 8; ++nf) {
        float b = bias[nf * 16 + lrow];
        acc[nf] = (f32x4){b, b, b, b};
    }
    #pragma unroll
    for (int nf = 0; nf < 8; ++nf)
        #pragma unroll
        for (int ks = 0; ks < 4; ++ks) {
            short8v bv = *(const short8v*)&wlds[nf * 16 + lrow][ks * 32 + kgrp * 8];
            acc[nf] = __builtin_amdgcn_mfma_f32_16x16x32_bf16(a[ks], bv, acc[nf], 0, 0, 0);
        }
}

// ---------------------------------------------------------------------------
// Node pre (MFMA): xi = ssp(ssp(feat)@Wi.T+bi) -> msg (f32)
//                  xja = ssp(ssp(feat)@Wj.T+bj) -> bf16
// ---------------------------------------------------------------------------
__global__ __launch_bounds__(256) void k_node_pre(
    const float* __restrict__ feat, const ushort_t* __restrict__ wbf,
    const float* __restrict__ bi, const float* __restrict__ bj,
    float* __restrict__ xi_out, ushort_t* __restrict__ xja_out)
{
    __shared__ ushort_t actA[64][136];
    __shared__ ushort_t wlds[128][136];
    const int t = threadIdx.x, lane = t & 63, w = t >> 6;
    const int lrow = lane & 15, kgrp = lane >> 4;
    const int row0 = blockIdx.x * 64;

    #pragma unroll
    for (int nf = 0; nf < 8; ++nf)
        #pragma unroll
        for (int r = 0; r < 4; ++r) {
            int gr = row0 + 16 * w + kgrp * 4 + r;
            float x = (gr < NA) ? feat[(size_t)gr * FDIM + 16 * nf + lrow] : 0.0f;
            actA[16 * w + kgrp * 4 + r][16 * nf + lrow] = f2bf(ssp_f(x));
        }
    __syncthreads();
    stage_w(wbf + 8192, wlds, t);
    __syncthreads();
    f32x4 acc[8];
    gemm_tile(actA, wlds, w, lrow, kgrp, bi, acc);
    #pragma unroll
    for (int nf = 0; nf < 8; ++nf)
        #pragma unroll
        for (int r = 0; r < 4; ++r) {
            int gr = row0 + 16 * w + kgrp * 4 + r;
            if (gr < NA)
                xi_out[(size_t)gr * FDIM + 16 * nf + lrow] = ssp_f(acc[nf][r]);
        }
    __syncthreads();
    stage_w(wbf + 24576, wlds, t);
    __syncthreads();
    gemm_tile(actA, wlds, w, lrow, kgrp, bj, acc);
    #pragma unroll
    for (int nf = 0; nf < 8; ++nf)
        #pragma unroll
        for (int r = 0; r < 4; ++r) {
            int gr = row0 + 16 * w + kgrp * 4 + r;
            if (gr < NA)
                xja_out[(size_t)gr * FDIM + 16 * nf + lrow] = f2bf(ssp_f(acc[nf][r]));
        }
}

// ---------------------------------------------------------------------------
// Edge GEMM, LDS-free: g[e][f] = desc[e]@Wdesc[f] (bf16 out). 128 edges/block.
// ---------------------------------------------------------------------------
__device__ __forceinline__ short8v pack8(const float* p) {
    short8v r;
    #pragma unroll
    for (int j = 0; j < 8; ++j) r[j] = (short)f2bf(p[j]);
    return r;
}

__global__ __launch_bounds__(256) void k_gemm_g(
    const float* __restrict__ desc, const ushort_t* __restrict__ wdbf,
    ushort_t* __restrict__ g, int nE)
{
    const int t = threadIdx.x, lane = t & 63, w = t >> 6;
    const int lrow = lane & 15, kgrp = lane >> 4;
    const int e0 = blockIdx.x * 128 + w * 32;

    short8v a[2][2];
    #pragma unroll
    for (int mt = 0; mt < 2; ++mt)
        #pragma unroll
        for (int ks = 0; ks < 2; ++ks) {
            int er = e0 + mt * 16 + lrow;
            if (er < nE) {
                const float* p = desc + (size_t)er * KDIM + ks * 32 + kgrp * 8;
                float tmp[8];
                *(float4*)(tmp)     = *(const float4*)p;
                *(float4*)(tmp + 4) = *(const float4*)(p + 4);
                a[mt][ks] = pack8(tmp);
            } else {
                a[mt][ks] = (short8v){0,0,0,0,0,0,0,0};
            }
        }

    f32x4 acc[2][8];
    #pragma unroll
    for (int mt = 0; mt < 2; ++mt)
        #pragma unroll
        for (int nf = 0; nf < 8; ++nf) acc[mt][nf] = (f32x4){0.f,0.f,0.f,0.f};

    #pragma unroll
    for (int nf = 0; nf < 8; ++nf) {
        const size_t wo = (size_t)(16 * nf + lrow) * KDIM + kgrp * 8;
        short8v b0 = *(const short8v*)(wdbf + wo);
        short8v b1 = *(const short8v*)(wdbf + wo + 32);
        #pragma unroll
        for (int mt = 0; mt < 2; ++mt) {
            acc[mt][nf] = __builtin_amdgcn_mfma_f32_16x16x32_bf16(a[mt][0], b0, acc[mt][nf], 0,0,0);
            acc[mt][nf] = __builtin_amdgcn_mfma_f32_16x16x32_bf16(a[mt][1], b1, acc[mt][nf], 0,0,0);
        }
    }

    #pragma unroll
    for (int mt = 0; mt < 2; ++mt)
        #pragma unroll
        for (int nf = 0; nf < 8; ++nf)
            #pragma unroll
            for (int r = 0; r < 4; ++r) {
                int er = e0 + mt * 16 + kgrp * 4 + r;
                if (er < nE)
                    g[(size_t)er * FDIM + 16 * nf + lrow] = f2bf(acc[mt][nf][r]);
            }
}

// ---------------------------------------------------------------------------
// Scatter: msg[i] += sum_seg g[e]*xja[idx_j[e]]  (block per atom, deterministic)
// 64 threads, u32-packed: lane t handles features 2t, 2t+1.
// ---------------------------------------------------------------------------
__global__ __launch_bounds__(64) void k_scatter(
    const ushort_t* __restrict__ g,
    const int* __restrict__ row_start,
    const int* __restrict__ idx_j,
    const ushort_t* __restrict__ xja,
    float* __restrict__ msg,
    int ce0, int ce1)
{
    const int i = blockIdx.x;
    const int t = threadIdx.x;
    int s = row_start[i], e = row_start[i + 1];
    if (s < ce0) s = ce0;
    if (e > ce1) e = ce1;
    if (s >= e) return;
    const uint_t* gp = (const uint_t*)g;
    const uint_t* xp = (const uint_t*)xja;
    float a0 = 0.0f, a1 = 0.0f;
    for (int k = s; k < e; ++k) {
        int jj = idx_j[k];
        uint_t gv = gp[(size_t)(k - ce0) * 64 + t];
        uint_t xv = xp[(size_t)jj * 64 + t];
        a0 += __uint_as_float(gv << 16) * __uint_as_float(xv << 16);
        a1 += __uint_as_float(gv & 0xFFFF0000u) * __uint_as_float(xv & 0xFFFF0000u);
    }
    float2* mp = (float2*)&msg[(size_t)i * FDIM + 2 * t];
    float2 mv = *mp;
    mv.x += a0; mv.y += a1;
    *mp = mv;
}

// ---------------------------------------------------------------------------
// Fallback fused edge kernel (tiny-ws only)
// ---------------------------------------------------------------------------
__global__ __launch_bounds__(128) void k_edge(
    const float* __restrict__ desc,
    const int* __restrict__ idx_i,
    const int* __restrict__ idx_j,
    const float* __restrict__ Wdesc,
    const ushort_t* __restrict__ xja,
    float* __restrict__ msg)
{
    const int i = blockIdx.x;
    const int t = threadIdx.x;
    int lo = 0, hi = NE;
    while (lo < hi) { int mid = (lo + hi) >> 1; if (idx_i[mid] < i) lo = mid + 1; else hi = mid; }
    int start = lo;
    hi = NE;
    while (lo < hi) { int mid = (lo + hi) >> 1; if (idx_i[mid] < i + 1) lo = mid + 1; else hi = mid; }
    int end = lo;
    start = __builtin_amdgcn_readfirstlane(start);
    end   = __builtin_amdgcn_readfirstlane(end);
    if (start >= end) return;
    float wreg[KDIM];
    #pragma unroll
    for (int q = 0; q < KDIM / 4; ++q) {
        float4 wv = *(const float4*)(Wdesc + (size_t)t * KDIM + 4 * q);
        wreg[4*q+0] = wv.x; wreg[4*q+1] = wv.y; wreg[4*q+2] = wv.z; wreg[4*q+3] = wv.w;
    }
    float acc = 0.0f;
    for (int e = start; e < end; ++e) {
        int jj = idx_j[e];
        const float* de = desc + (size_t)e * KDIM;
        float dot = 0.0f;
        #pragma unroll
        for (int q = 0; q < KDIM / 4; ++q) {
            float4 dv = *(const float4*)(de + 4 * q);
            dot += dv.x * wreg[4*q] + dv.y * wreg[4*q+1]
                 + dv.z * wreg[4*q+2] + dv.w * wreg[4*q+3];
        }
        acc += dot * bf2f(xja[(size_t)jj * FDIM + t]);
    }
    msg[(size_t)i * FDIM + t] += acc;
}

// ---------------------------------------------------------------------------
// Fused node chain: 3 residuals + outmix + 2 residuals, m carried in registers.
// ---------------------------------------------------------------------------
__device__ __forceinline__ void write_act(
    ushort_t (*actA)[136], int w, int lrow, int kgrp, const float v[8][4])
{
    #pragma unroll
    for (int nf = 0; nf < 8; ++nf)
        #pragma unroll
        for (int r = 0; r < 4; ++r)
            actA[16 * w + kgrp * 4 + r][16 * nf + lrow] = f2bf(ssp_f(v[nf][r]));
}

__global__ __launch_bounds__(256) void k_chain(
    const float* __restrict__ msgp, const float* __restrict__ feat,
    const float* __restrict__ u, const ushort_t* __restrict__ wch,
    const float* __restrict__ bri1, const float* __restrict__ bri2,
    const float* __restrict__ bd,
    const float* __restrict__ bra1, const float* __restrict__ bra2,
    float* __restrict__ xout)
{
    __shared__ ushort_t actA[64][136];
    __shared__ ushort_t wlds[128][136];
    const int t = threadIdx.x, lane = t & 63, w = t >> 6;
    const int lrow = lane & 15, kgrp = lane >> 4;
    const int row0 = blockIdx.x * 64;

    float m[8][4];
    #pragma unroll
    for (int nf = 0; nf < 8; ++nf)
        #pragma unroll
        for (int r = 0; r < 4; ++r) {
            int gr = row0 + 16 * w + kgrp * 4 + r;
            m[nf][r] = (gr < NA) ? msgp[(size_t)gr * FDIM + 16 * nf + lrow] : 0.0f;
        }

    f32x4 acc[8];
    float h[8][4];

    // --- 3 interaction residuals ---
    for (int k = 0; k < NRI; ++k) {
        write_act(actA, w, lrow, kgrp, m);
        __syncthreads();
        stage_w(wch + (size_t)(2 * k) * 16384, wlds, t);
        __syncthreads();
        gemm_tile(actA, wlds, w, lrow, kgrp, bri1 + k * FDIM, acc);
        #pragma unroll
        for (int nf = 0; nf < 8; ++nf)
            #pragma unroll
            for (int r = 0; r < 4; ++r) h[nf][r] = acc[nf][r];
        write_act(actA, w, lrow, kgrp, h);
        __syncthreads();
        stage_w(wch + (size_t)(2 * k + 1) * 16384, wlds, t);
        __syncthreads();
        gemm_tile(actA, wlds, w, lrow, kgrp, bri2 + k * FDIM, acc);
        #pragma unroll
        for (int nf = 0; nf < 8; ++nf)
            #pragma unroll
            for (int r = 0; r < 4; ++r) m[nf][r] += acc[nf][r];
    }

    // --- outmix: m = u*feat + ssp(m)@Wd.T + bd ---
    write_act(actA, w, lrow, kgrp, m);
    __syncthreads();
    stage_w(wch + (size_t)6 * 16384, wlds, t);
    __syncthreads();
    gemm_tile(actA, wlds, w, lrow, kgrp, bd, acc);
    #pragma unroll
    for (int nf = 0; nf < 8; ++nf)
        #pragma unroll
        for (int r = 0; r < 4; ++r) {
            int gr = row0 + 16 * w + kgrp * 4 + r;
            float fv = (gr < NA) ? feat[(size_t)gr * FDIM + 16 * nf + lrow] : 0.0f;
            m[nf][r] = u[16 * nf + lrow] * fv + acc[nf][r];
        }

    // --- 2 atomic residuals ---
    for (int k = 0; k < NRA; ++k) {
        write_act(actA, w, lrow, kgrp, m);
        __syncthreads();
        stage_w(wch + (size_t)(7 + 2 * k) * 16384, wlds, t);
        __syncthreads();
        gemm_tile(actA, wlds, w, lrow, kgrp, bra1 + k * FDIM, acc);
        #pragma unroll
        for (int nf = 0; nf < 8; ++nf)
            #pragma unroll
            for (int r = 0; r < 4; ++r) h[nf][r] = acc[nf][r];
        write_act(actA, w, lrow, kgrp, h);
        __syncthreads();
        stage_w(wch + (size_t)(8 + 2 * k) * 16384, wlds, t);
        __syncthreads();
        gemm_tile(actA, wlds, w, lrow, kgrp, bra2 + k * FDIM, acc);
        #pragma unroll
        for (int nf = 0; nf < 8; ++nf)
            #pragma unroll
            for (int r = 0; r < 4; ++r) m[nf][r] += acc[nf][r];
    }

    #pragma unroll
    for (int nf = 0; nf < 8; ++nf)
        #pragma unroll
        for (int r = 0; r < 4; ++r) {
            int gr = row0 + 16 * w + kgrp * 4 + r;
            if (gr < NA)
                xout[(size_t)gr * FDIM + 16 * nf + lrow] = m[nf][r];
        }
}

// ---------------------------------------------------------------------------
extern "C" void kernel_launch(void* const* d_in, const int* in_sizes, int n_in,
                              void* d_out, int out_size, void* d_ws, size_t ws_size,
                              hipStream_t stream)
{
    const float* feat  = (const float*)d_in[0];
    const float* desc  = (const float*)d_in[1];
    const int*   idx_i = (const int*)d_in[2];
    const int*   idx_j = (const int*)d_in[3];
    const float* Wdesc = (const float*)d_in[4];
    const float* Wi    = (const float*)d_in[5];
    const float* bi    = (const float*)d_in[6];
    const float* Wj    = (const float*)d_in[7];
    const float* bj    = (const float*)d_in[8];
    const float* Wri1  = (const float*)d_in[9];
    const float* bri1  = (const float*)d_in[10];
    const float* Wri2  = (const float*)d_in[11];
    const float* bri2  = (const float*)d_in[12];
    const float* Wd    = (const float*)d_in[13];
    const float* bd    = (const float*)d_in[14];
    const float* u     = (const float*)d_in[15];
    const float* Wra1  = (const float*)d_in[16];
    const float* bra1  = (const float*)d_in[17];
    const float* Wra2  = (const float*)d_in[18];
    const float* bra2  = (const float*)d_in[19];

    char* wsp = (char*)d_ws;
    float* msg = (float*)wsp;
    size_t off = (size_t)NA * FDIM * sizeof(float);
    ushort_t* xja = (ushort_t*)(wsp + off);
    off += (size_t)NA * FDIM * sizeof(ushort_t);
    int* row_start = (int*)(wsp + off);
    off += (((size_t)(NA + 1) * sizeof(int)) + 255) & ~(size_t)255;
    ushort_t* wbf = (ushort_t*)(wsp + off);
    off += (((size_t)221184 * sizeof(ushort_t)) + 255) & ~(size_t)255;
    ushort_t* gbuf = (ushort_t*)(wsp + off);
    size_t avail = (ws_size > off) ? ws_size - off : 0;
    size_t max_chunk = (avail / ((size_t)FDIM * sizeof(ushort_t))) & ~(size_t)127;

    float* xout = (float*)d_out;
    const int nblk64 = (NA + 63) / 64;

    k_wconv<<<dim3(24, 8), 256, 0, stream>>>(Wdesc, Wi, Wj, Wri1, Wri2, Wd, Wra1, Wra2, wbf);
    k_row_starts<<<(NA + 256) / 256, 256, 0, stream>>>(idx_i, row_start);
    k_node_pre<<<nblk64, 256, 0, stream>>>(feat, wbf, bi, bj, msg, xja);

    if (max_chunk >= 128) {
        for (size_t ce0 = 0; ce0 < NE; ce0 += max_chunk) {
            size_t ce1 = ce0 + max_chunk; if (ce1 > NE) ce1 = NE;
            int n = (int)(ce1 - ce0);
            k_gemm_g<<<(n + 127) / 128, 256, 0, stream>>>(desc + ce0 * KDIM, wbf, gbuf, n);
            k_scatter<<<NA, 64, 0, stream>>>(gbuf, row_start, idx_j, xja, msg,
                                             (int)ce0, (int)ce1);
        }
    } else {
        k_edge<<<NA, 128, 0, stream>>>(desc, idx_i, idx_j, Wdesc, xja, msg);
    }

    k_chain<<<nblk64, 256, 0, stream>>>(msg, feat, u, wbf + 40960,
                                        bri1, bri2, bd, bra1, bra2, xout);
}